// Round 7
// baseline (292.938 us; speedup 1.0000x reference)
//
#include <hip/hip_runtime.h>
#include <math.h>

#define NSAMP 262144
#define NW 8              // waves per block (BLK=512)
#define BLK 512
// r13: BLK=512, GRID=1024 -> 4 blocks/CU (LDS 26112*4=104448 <= 163840),
// 32 waves/CU (VGPR<=64 == 512/8 budget). Uniform work: every wave does
// 2 PHYS iters + 1 DATA2 iter (DATA CH=2 = 32 samples/iter, 8192 iters).
// r14: overhead strip (neutral -- compiler had already done it).
// r15 (FAILED): mask 0x127 with waves_per_eu(2,8) -> compiler spent 68 VGPR,
//   occupancy cliff 37->21%, 77->94.5us. Regression was pure occupancy.
// r16: retry mask 0x127 with waves_per_eu(8,8): HARD floor of 8 waves/EU
//   forces the allocator to fit 64 VGPR, so VALU-crossing freedom operates
//   inside the fixed budget (what r15 meant to test).
#define GRID 1024
#define TOTW (GRID * NW)  // 8192 waves

#define SB_MASK 0x127     // ALU/VALU/SALU + VMEM_READ/DS_READ may cross; MFMA/DS-writes pinned

typedef _Float16 f16x8 __attribute__((ext_vector_type(8)));
typedef __fp16   fp16x2 __attribute__((ext_vector_type(2)));
typedef float    f32x4 __attribute__((ext_vector_type(4)));
typedef float    f32x2 __attribute__((ext_vector_type(2)));
typedef unsigned int u32;

// PHYS channels = {0:val, 1:d/dx, 2:d/dy, 3:combo z* = z_t - alpha*(z_xx+z_yy)}
// combo closed under propagation: h* = ap*z* - alpha*app*(z1^2+z2^2); residual = W4^T h*.
// DATA channels = independent 16-sample groups (CH=2).
#define PCH 4

#define TWO_LOG2E 2.8853900817779268f   // 2*log2(e): expf(2x) = exp2(x*TWO_LOG2E)

// B-fragment as raw dwords: cvt_pkrtz output dwords are written straight into
// d[] with constant indices -> pure register naming, no f16 element inserts.
union BFrag { f16x8 v[2]; u32 d[8]; };

__device__ __forceinline__ f32x2 lo2(f32x4 v) { return __builtin_shufflevector(v, v, 0, 1); }
__device__ __forceinline__ f32x2 hi2(f32x4 v) { return __builtin_shufflevector(v, v, 2, 3); }
__device__ __forceinline__ f32x2 splat2(float s) { f32x2 v; v.x = s; v.y = s; return v; }

__device__ __forceinline__ u32 pkdw(f32x2 p) {
    union { fp16x2 h; u32 u; } c;
    c.h = __builtin_amdgcn_cvt_pkrtz(p.x, p.y);
    return c.u;
}

// pair tanh (r13: trans pipe has slack; full-rate VALU is binding -> keep the
// minimal 3-full-rate/4-trans form, do NOT rcp-pair).
__device__ __forceinline__ f32x2 fast_tanh2(f32x2 x) {
    f32x2 t = x * splat2(TWO_LOG2E);
    f32x2 e;
    e.x = __builtin_amdgcn_exp2f(t.x);
    e.y = __builtin_amdgcn_exp2f(t.y);
    f32x2 d = e + splat2(1.0f);
    f32x2 rc;
    rc.x = __builtin_amdgcn_rcpf(d.x);
    rc.y = __builtin_amdgcn_rcpf(d.y);
    return splat2(1.0f) - splat2(2.0f) * rc;
}

// PHYS pointwise on an r-pair: z* channels in, h* channels out (packed math).
__device__ __forceinline__ void phys_half(f32x2 z0, f32x2 z1, f32x2 z2, f32x2 z3,
                                          f32x2 alpha2, f32x2 (&h)[PCH])
{
    f32x2 a    = fast_tanh2(z0);
    f32x2 ap   = splat2(1.0f) - a * a;
    f32x2 napp = (a * ap) * alpha2;          // = -alpha*app = 2*alpha*a*ap
    h[0] = a;
    h[1] = ap * z1;
    h[2] = ap * z2;
    f32x2 s = z1 * z1 + z2 * z2;
    h[3] = ap * z3 + napp * s;
}

// Final-fold variant: only h[3] is consumed (r14: drops h1/h2 products).
// h3 math is op-for-op identical to phys_half's h[3].
__device__ __forceinline__ f32x2 phys_resid(f32x2 z0, f32x2 z1, f32x2 z2, f32x2 z3,
                                            f32x2 alpha2)
{
    f32x2 a    = fast_tanh2(z0);
    f32x2 ap   = splat2(1.0f) - a * a;
    f32x2 napp = (a * ap) * alpha2;
    f32x2 s = z1 * z1 + z2 * z2;
    return ap * z3 + napp * s;
}

__device__ __forceinline__ double shfl_xor_d(double v, int m) {
    union { double d; int i[2]; } u; u.d = v;
    u.i[0] = __shfl_xor(u.i[0], m, 64);
    u.i[1] = __shfl_xor(u.i[1], m, 64);
    return u.d;
}

// pointwise on one rt's acc[CH] -> two dwords per channel, written in place.
template<bool DATA, int CH>
__device__ __forceinline__ void pw_store(const f32x4* acc, BFrag (&bout)[CH],
                                         int rt, f32x2 alpha2)
{
    if constexpr (DATA) {
        #pragma unroll
        for (int c = 0; c < CH; c++) {
            bout[c].d[rt * 2 + 0] = pkdw(fast_tanh2(lo2(acc[c])));
            bout[c].d[rt * 2 + 1] = pkdw(fast_tanh2(hi2(acc[c])));
        }
    } else {
        f32x2 hlo[PCH], hhi[PCH];
        phys_half(lo2(acc[0]), lo2(acc[1]), lo2(acc[2]), lo2(acc[3]), alpha2, hlo);
        phys_half(hi2(acc[0]), hi2(acc[1]), hi2(acc[2]), hi2(acc[3]), alpha2, hhi);
        #pragma unroll
        for (int c = 0; c < CH; c++) {
            bout[c].d[rt * 2 + 0] = pkdw(hlo[c]);
            bout[c].d[rt * 2 + 1] = pkdw(hhi[c]);
        }
    }
}

template<bool DATA, int CH>
__device__ __forceinline__ void layer_mfma(
    const _Float16* sWA, const float (*sB)[64],
    int l, int rt, int q, int n, const BFrag (&bf)[CH], f32x4 (&acc)[CH])
{
    const f32x4 z4 = {0.f, 0.f, 0.f, 0.f};
    f16x8 a0k = *(const f16x8*)&sWA[((((l * 4 + rt) * 2 + 0) * 4 + q) * 16 + n) * 8];
    f16x8 a1k = *(const f16x8*)&sWA[((((l * 4 + rt) * 2 + 1) * 4 + q) * 16 + n) * 8];
    f32x4 bias = *(const f32x4*)&sB[l + 1][rt * 16 + q * 4];
    #pragma unroll
    for (int c = 0; c < CH; c++) {
        f32x4 cin = (DATA || c == 0) ? bias : z4;
        acc[c] = __builtin_amdgcn_mfma_f32_16x16x32_f16(a0k, bf[c].v[0], cin, 0, 0, 0);
        acc[c] = __builtin_amdgcn_mfma_f32_16x16x32_f16(a1k, bf[c].v[1], acc[c], 0, 0, 0);
    }
}

template<bool DATA, int CH>
__device__ __forceinline__ void hidden_layer(
    const _Float16* sWA, const float (*sB)[64],
    int l, int q, int n, const BFrag (&bin)[CH], BFrag (&bout)[CH], f32x2 alpha2)
{
    #pragma unroll
    for (int rt = 0; rt < 4; rt++) {
        f32x4 acc[CH];
        layer_mfma<DATA, CH>(sWA, sB, l, rt, q, n, bin, acc);
        pw_store<DATA, CH>(acc, bout, rt, alpha2);
        // r16: VALU/SALU may cross; MFMA/DS-writes stay pinned; pressure
        // contained by the hard waves_per_eu(8,8) floor.
        __builtin_amdgcn_sched_barrier(SB_MASK);
    }
}

template<bool DATA, int CH>
__device__ __forceinline__ double run_mode(
    const float* __restrict__ xd, const float* __restrict__ yd,
    const float* __restrict__ xp, float alpha,
    const _Float16* sWA, const f16x8 (&a0r)[4],
    const float (*sB)[64], const float* sW4, float b4,
    int q, int n, int wstart, int wstride)
{
    const f32x4 z4 = {0.f, 0.f, 0.f, 0.f};
    const f32x2 alpha2 = splat2(2.0f * alpha);

    const int SPI = DATA ? (16 * CH) : 16;     // samples per iter
    const int NIT = NSAMP / SPI;
    double dacc = 0.0;

    // r14: pointer walks instead of per-iter index math.
    const float* px = (DATA ? xd : xp) + (size_t)(wstart * SPI + n) * 3;
    const float* py = yd + (size_t)(wstart * SPI) + n;
    const size_t xstep = (size_t)wstride * SPI * 3;
    const size_t ystep = (size_t)wstride * SPI;

    for (int it = wstart; it < NIT; it += wstride) {
        BFrag bfA[CH], bfB[CH];             // ping-pong, always constant-indexed
        // ---------------- layer 0 (K=32 padded, k<3 nonzero; A-frags in regs) ----------------
        {
            f16x8 b0f[CH];
            #pragma unroll
            for (int c = 0; c < CH; c++) {
                union { f16x8 v; u32 dd[4]; _Float16 h[8]; } u;
                u.dd[0] = u.dd[1] = u.dd[2] = u.dd[3] = 0u;
                if (DATA) {
                    if (q == 0) {
                        const float* pc = px + c * 48;   // c*16 samples * 3
                        u.h[0] = (_Float16)pc[0];
                        u.h[1] = (_Float16)pc[1];
                        u.h[2] = (_Float16)pc[2];
                    }
                } else {
                    if (c == 0) {
                        if (q == 0) {
                            u.h[0] = (_Float16)px[0];
                            u.h[1] = (_Float16)px[1];
                            u.h[2] = (_Float16)px[2];
                        }
                    } else if (q == 0) {
                        // seeds: c=1 -> elem0=1 (d/dx), c=2 -> elem1=1 (d/dy),
                        //        c=3 -> elem2=1 (combo z*0 = z_t)
                        if (c == 1) u.dd[0] = 0x00003C00u;
                        if (c == 2) u.dd[0] = 0x3C000000u;
                        if (c == 3) u.dd[1] = 0x00003C00u;
                    }
                }
                b0f[c] = u.v;
            }
            #pragma unroll
            for (int rt = 0; rt < 4; rt++) {
                f32x4 bias = *(const f32x4*)&sB[0][rt * 16 + q * 4];
                f32x4 acc[CH];
                if (DATA) {
                    #pragma unroll
                    for (int c = 0; c < CH; c++)
                        acc[c] = __builtin_amdgcn_mfma_f32_16x16x32_f16(a0r[rt], b0f[c], bias, 0, 0, 0);
                } else {
                    acc[0] = __builtin_amdgcn_mfma_f32_16x16x32_f16(a0r[rt], b0f[0], bias, 0, 0, 0);
                    #pragma unroll
                    for (int c = 1; c < CH; c++)
                        acc[c] = __builtin_amdgcn_mfma_f32_16x16x32_f16(a0r[rt], b0f[c], z4, 0, 0, 0);
                }
                pw_store<DATA, CH>(acc, bfA, rt, alpha2);
                __builtin_amdgcn_sched_barrier(SB_MASK);
            }
        }

        // ---------------- hidden layers, manually unrolled ping-pong ----------------
        hidden_layer<DATA, CH>(sWA, sB, 0, q, n, bfA, bfB, alpha2);
        hidden_layer<DATA, CH>(sWA, sB, 1, q, n, bfB, bfA, alpha2);

        // ---------------- last hidden layer + fold 64->1 into partials ----------------
        f32x2 t2[CH];                              // DATA partials (pair accumulators)
        #pragma unroll
        for (int c = 0; c < CH; c++) t2[c] = splat2(0.f);
        f32x2 tr2 = splat2(0.f);                   // PHYS residual pair accumulator
        #pragma unroll
        for (int rt = 0; rt < 4; rt++) {
            f32x4 acc[CH];
            layer_mfma<DATA, CH>(sWA, sB, 2, rt, q, n, bfA, acc);
            f32x4 w4v = *(const f32x4*)&sW4[rt * 16 + q * 4];
            f32x2 wlo = lo2(w4v), whi = hi2(w4v);
            if (DATA) {
                #pragma unroll
                for (int c = 0; c < CH; c++) {
                    t2[c] = t2[c] + wlo * fast_tanh2(lo2(acc[c]));
                    t2[c] = t2[c] + whi * fast_tanh2(hi2(acc[c]));
                }
            } else {
                tr2 = tr2 + wlo * phys_resid(lo2(acc[0]), lo2(acc[1]), lo2(acc[2]), lo2(acc[3]), alpha2);
                tr2 = tr2 + whi * phys_resid(hi2(acc[0]), hi2(acc[1]), hi2(acc[2]), hi2(acc[3]), alpha2);
            }
        }

        // ---------------- epilogue ----------------
        if (DATA) {
            float t[CH];
            #pragma unroll
            for (int c = 0; c < CH; c++) {
                t[c] = t2[c].x + t2[c].y;
                t[c] += __shfl_xor(t[c], 16, 64);
                t[c] += __shfl_xor(t[c], 32, 64);
            }
            if (q == 0) {
                #pragma unroll
                for (int c = 0; c < CH; c++) {
                    float d = t[c] + b4 - py[c * 16];
                    dacc += (double)d * (double)d;
                }
            }
        } else {
            float tr = tr2.x + tr2.y;
            tr += __shfl_xor(tr, 16, 64);
            tr += __shfl_xor(tr, 32, 64);
            if (q == 0) dacc += (double)tr * (double)tr;
        }

        px += xstep;
        py += ystep;
    }
    return dacc;
}

// waves_per_eu(8,8): HARD 8-waves/EU floor -> allocator must fit 64 VGPR.
// 32 waves/CU with 4 blocks/CU (LDS 104448 <= 160KiB). r13/r14 live set = 60.
__global__ __launch_bounds__(BLK)
__attribute__((amdgpu_waves_per_eu(8, 8)))
void fused_kernel(
    const float* __restrict__ xd, const float* __restrict__ yd, const float* __restrict__ xp,
    const float* __restrict__ W0, const float* __restrict__ b0,
    const float* __restrict__ W1, const float* __restrict__ b1,
    const float* __restrict__ W2, const float* __restrict__ b2,
    const float* __restrict__ W3, const float* __restrict__ b3,
    const float* __restrict__ W4, const float* __restrict__ b4,
    const float* __restrict__ log_alpha,
    double* __restrict__ accg)     // accg[2*bid+0]=phys partial, [2*bid+1]=data partial
{
    __shared__ __align__(16) _Float16 sWA[3 * 4 * 2 * 4 * 16 * 8];   // 24576 B
    __shared__ __align__(16) float sB[4][64];
    __shared__ __align__(16) float sW4s[64];
    __shared__ float sb4;
    __shared__ double sRedP[NW], sRedD[NW];

    const int tid = threadIdx.x;
    // Hidden-layer A-frags with neuron relabel p(k):
    //   A_l[m][k] = W_l[p(k)][m],  p(k) = rt*16 + q*4 + r,
    //   rt = 2*(k>>5) + ((k>>2)&1), q = (k>>3)&3, r = k&3.
    // Makes the C->B layer transition lane-local (verified absmax 0.0, r5-r15).
    for (int idx = tid; idx < 3 * 4096; idx += BLK) {
        int l = idx >> 12, rem = idx & 4095, k = rem >> 6, m = rem & 63;
        const float* Ws = (l == 0) ? W1 : (l == 1) ? W2 : W3;   // [in][out]
        int pk_ = (2 * (k >> 5) + ((k >> 2) & 1)) * 16 + ((k >> 3) & 3) * 4 + (k & 3);
        int rt = m >> 4, mlo = m & 15, kt = k >> 5, qq = (k >> 3) & 3, j = k & 7;
        sWA[((((l * 4 + rt) * 2 + kt) * 4 + qq) * 16 + mlo) * 8 + j] = (_Float16)Ws[pk_ * 64 + m];
    }
    for (int i = tid; i < 64; i += BLK) {
        sB[0][i] = b0[i]; sB[1][i] = b1[i]; sB[2][i] = b2[i]; sB[3][i] = b3[i];
        sW4s[i] = W4[i];
    }
    if (tid == 0) sb4 = b4[0];

    const int wave = tid >> 6, lane = tid & 63;
    const int q = lane >> 4, n = lane & 15;
    const float alpha = __expf(log_alpha[0]);

    // layer-0 A-frags in registers (loop-invariant; only q==0 lanes non-zero).
    f16x8 a0r[4];
    #pragma unroll
    for (int rt = 0; rt < 4; rt++) {
        f16x8 v = {0, 0, 0, 0, 0, 0, 0, 0};
        if (q == 0) {
            v[0] = (_Float16)W0[0 * 64 + rt * 16 + n];
            v[1] = (_Float16)W0[1 * 64 + rt * 16 + n];
            v[2] = (_Float16)W0[2 * 64 + rt * 16 + n];
        }
        a0r[rt] = v;
    }
    __syncthreads();

    // Uniform per-wave work: 2 PHYS iters + 1 DATA2 iter, every wave.
    const int wid = blockIdx.x * NW + wave;
    double dp = run_mode<false, 4>(xd, yd, xp, alpha, sWA, a0r, sB, sW4s, sb4,
                                   q, n, wid, TOTW);
    double dd = run_mode<true, 2>(xd, yd, xp, alpha, sWA, a0r, sB, sW4s, sb4,
                                  q, n, wid, TOTW);
    #pragma unroll
    for (int m = 1; m < 64; m <<= 1) {
        dp = dp + shfl_xor_d(dp, m);
        dd = dd + shfl_xor_d(dd, m);
    }
    if (lane == 0) { sRedP[wave] = dp; sRedD[wave] = dd; }
    __syncthreads();
    if (tid == 0) {
        double sp = 0.0, sd = 0.0;
        #pragma unroll
        for (int w = 0; w < NW; w++) { sp += sRedP[w]; sd += sRedD[w]; }
        accg[2 * blockIdx.x + 0] = sp;
        accg[2 * blockIdx.x + 1] = sd;
    }
}

__global__ void finalize_kernel(const double* __restrict__ ws,
                                const float* __restrict__ log_lambda,
                                const float* __restrict__ log_alpha,
                                float* __restrict__ out)
{
    __shared__ double sp[256], sd[256];
    int tid = threadIdx.x;
    double pd = 0.0, dd = 0.0;
    for (int i = tid; i < GRID; i += 256) {
        pd += ws[2 * i + 0];
        dd += ws[2 * i + 1];
    }
    sp[tid] = pd; sd[tid] = dd;
    __syncthreads();
    for (int s = 128; s > 0; s >>= 1) {
        if (tid < s) { sp[tid] += sp[tid + s]; sd[tid] += sd[tid + s]; }
        __syncthreads();
    }
    if (tid == 0) {
        float pde_loss  = (float)(sp[0] / (double)NSAMP);
        float data_loss = (float)(sd[0] / (double)NSAMP);
        float alpha = expf(log_alpha[0]);
        float lam   = expf(log_lambda[0]);
        out[0] = data_loss + lam * pde_loss;
        out[1] = data_loss;
        out[2] = pde_loss;
        out[3] = alpha;
        out[4] = lam;
    }
}

extern "C" void kernel_launch(void* const* d_in, const int* in_sizes, int n_in,
                              void* d_out, int out_size, void* d_ws, size_t ws_size,
                              hipStream_t stream) {
    const float* xd = (const float*)d_in[0];
    const float* yd = (const float*)d_in[1];
    const float* xp = (const float*)d_in[2];
    const float* W0 = (const float*)d_in[3];
    const float* b0 = (const float*)d_in[4];
    const float* W1 = (const float*)d_in[5];
    const float* b1 = (const float*)d_in[6];
    const float* W2 = (const float*)d_in[7];
    const float* b2 = (const float*)d_in[8];
    const float* W3 = (const float*)d_in[9];
    const float* b3 = (const float*)d_in[10];
    const float* W4 = (const float*)d_in[11];
    const float* b4 = (const float*)d_in[12];
    const float* log_lambda = (const float*)d_in[13];
    const float* log_alpha  = (const float*)d_in[14];
    float* out = (float*)d_out;
    double* acc = (double*)d_ws;   // 2*GRID doubles of per-block partials

    fused_kernel<<<GRID, BLK, 0, stream>>>(xd, yd, xp, W0, b0, W1, b1, W2, b2, W3, b3,
                                           W4, b4, log_alpha, acc);
    finalize_kernel<<<1, 256, 0, stream>>>(acc, log_lambda, log_alpha, out);
}

// Round 8
// 151.121 us; speedup vs baseline: 1.9384x; 1.9384x over previous
//
#include <hip/hip_runtime.h>
#include <math.h>

#define NSAMP 262144
#define NW 8              // waves per block (BLK=512)
#define BLK 512
// r13: BLK=512, GRID=1024 -> 4 blocks/CU, 32 waves/CU target (VGPR<=64).
// Uniform work: every wave does 2 PHYS iters + 1 DATA2 iter.
// r15 (FAILED): mask 0x127 @ (2,8) -> 68 VGPR, occupancy cliff, 94us.
// r16 (FAILED): mask 0x127 @ (8,8) -> allocator shrank to 32 VGPR by
//   SPILLING (254MB fetch / 442MB write scratch traffic, 215us). Scheduling
//   axis closed: 0x120 @ (2,8) with 60 VGPR is the proven optimum (77us).
// r17: PHYS layer-0 hoist. Channels 1-3 of layer 0 are one-hot-B MFMAs:
//   acc[c][j] = (f32)(f16)W0[c-1][rt*16+q*4+j], sample-independent. Replace
//   12 of 112 PHYS MFMAs/iter with ds_read_b128 from pre-rounded sW0r
//   (bit-exact: one-term f16*1.0 sum into C=0 is exact f32 promotion).
#define GRID 1024
#define TOTW (GRID * NW)  // 8192 waves

// sched_barrier mask: DS/VMEM reads may cross; VALU/MFMA/DS-writes pinned.
#define SB_MASK 0x120

typedef _Float16 f16x8 __attribute__((ext_vector_type(8)));
typedef __fp16   fp16x2 __attribute__((ext_vector_type(2)));
typedef float    f32x4 __attribute__((ext_vector_type(4)));
typedef float    f32x2 __attribute__((ext_vector_type(2)));
typedef unsigned int u32;

// PHYS channels = {0:val, 1:d/dx, 2:d/dy, 3:combo z* = z_t - alpha*(z_xx+z_yy)}
// combo closed under propagation: h* = ap*z* - alpha*app*(z1^2+z2^2); residual = W4^T h*.
// DATA channels = independent 16-sample groups (CH=2).
#define PCH 4

#define TWO_LOG2E 2.8853900817779268f   // 2*log2(e): expf(2x) = exp2(x*TWO_LOG2E)

// B-fragment as raw dwords: cvt_pkrtz output dwords are written straight into
// d[] with constant indices -> pure register naming, no f16 element inserts.
union BFrag { f16x8 v[2]; u32 d[8]; };

__device__ __forceinline__ f32x2 lo2(f32x4 v) { return __builtin_shufflevector(v, v, 0, 1); }
__device__ __forceinline__ f32x2 hi2(f32x4 v) { return __builtin_shufflevector(v, v, 2, 3); }
__device__ __forceinline__ f32x2 splat2(float s) { f32x2 v; v.x = s; v.y = s; return v; }

__device__ __forceinline__ u32 pkdw(f32x2 p) {
    union { fp16x2 h; u32 u; } c;
    c.h = __builtin_amdgcn_cvt_pkrtz(p.x, p.y);
    return c.u;
}

// pair tanh (r13: trans pipe has slack; full-rate VALU is binding -> keep the
// minimal 3-full-rate/4-trans form, do NOT rcp-pair).
__device__ __forceinline__ f32x2 fast_tanh2(f32x2 x) {
    f32x2 t = x * splat2(TWO_LOG2E);
    f32x2 e;
    e.x = __builtin_amdgcn_exp2f(t.x);
    e.y = __builtin_amdgcn_exp2f(t.y);
    f32x2 d = e + splat2(1.0f);
    f32x2 rc;
    rc.x = __builtin_amdgcn_rcpf(d.x);
    rc.y = __builtin_amdgcn_rcpf(d.y);
    return splat2(1.0f) - splat2(2.0f) * rc;
}

// PHYS pointwise on an r-pair: z* channels in, h* channels out (packed math).
__device__ __forceinline__ void phys_half(f32x2 z0, f32x2 z1, f32x2 z2, f32x2 z3,
                                          f32x2 alpha2, f32x2 (&h)[PCH])
{
    f32x2 a    = fast_tanh2(z0);
    f32x2 ap   = splat2(1.0f) - a * a;
    f32x2 napp = (a * ap) * alpha2;          // = -alpha*app = 2*alpha*a*ap
    h[0] = a;
    h[1] = ap * z1;
    h[2] = ap * z2;
    f32x2 s = z1 * z1 + z2 * z2;
    h[3] = ap * z3 + napp * s;
}

// Final-fold variant: only h[3] is consumed (r14: drops h1/h2 products).
// h3 math is op-for-op identical to phys_half's h[3].
__device__ __forceinline__ f32x2 phys_resid(f32x2 z0, f32x2 z1, f32x2 z2, f32x2 z3,
                                            f32x2 alpha2)
{
    f32x2 a    = fast_tanh2(z0);
    f32x2 ap   = splat2(1.0f) - a * a;
    f32x2 napp = (a * ap) * alpha2;
    f32x2 s = z1 * z1 + z2 * z2;
    return ap * z3 + napp * s;
}

__device__ __forceinline__ double shfl_xor_d(double v, int m) {
    union { double d; int i[2]; } u; u.d = v;
    u.i[0] = __shfl_xor(u.i[0], m, 64);
    u.i[1] = __shfl_xor(u.i[1], m, 64);
    return u.d;
}

// pointwise on one rt's acc[CH] -> two dwords per channel, written in place.
template<bool DATA, int CH>
__device__ __forceinline__ void pw_store(const f32x4* acc, BFrag (&bout)[CH],
                                         int rt, f32x2 alpha2)
{
    if constexpr (DATA) {
        #pragma unroll
        for (int c = 0; c < CH; c++) {
            bout[c].d[rt * 2 + 0] = pkdw(fast_tanh2(lo2(acc[c])));
            bout[c].d[rt * 2 + 1] = pkdw(fast_tanh2(hi2(acc[c])));
        }
    } else {
        f32x2 hlo[PCH], hhi[PCH];
        phys_half(lo2(acc[0]), lo2(acc[1]), lo2(acc[2]), lo2(acc[3]), alpha2, hlo);
        phys_half(hi2(acc[0]), hi2(acc[1]), hi2(acc[2]), hi2(acc[3]), alpha2, hhi);
        #pragma unroll
        for (int c = 0; c < CH; c++) {
            bout[c].d[rt * 2 + 0] = pkdw(hlo[c]);
            bout[c].d[rt * 2 + 1] = pkdw(hhi[c]);
        }
    }
}

template<bool DATA, int CH>
__device__ __forceinline__ void layer_mfma(
    const _Float16* sWA, const float (*sB)[64],
    int l, int rt, int q, int n, const BFrag (&bf)[CH], f32x4 (&acc)[CH])
{
    const f32x4 z4 = {0.f, 0.f, 0.f, 0.f};
    f16x8 a0k = *(const f16x8*)&sWA[((((l * 4 + rt) * 2 + 0) * 4 + q) * 16 + n) * 8];
    f16x8 a1k = *(const f16x8*)&sWA[((((l * 4 + rt) * 2 + 1) * 4 + q) * 16 + n) * 8];
    f32x4 bias = *(const f32x4*)&sB[l + 1][rt * 16 + q * 4];
    #pragma unroll
    for (int c = 0; c < CH; c++) {
        f32x4 cin = (DATA || c == 0) ? bias : z4;
        acc[c] = __builtin_amdgcn_mfma_f32_16x16x32_f16(a0k, bf[c].v[0], cin, 0, 0, 0);
        acc[c] = __builtin_amdgcn_mfma_f32_16x16x32_f16(a1k, bf[c].v[1], acc[c], 0, 0, 0);
    }
}

template<bool DATA, int CH>
__device__ __forceinline__ void hidden_layer(
    const _Float16* sWA, const float (*sB)[64],
    int l, int q, int n, const BFrag (&bin)[CH], BFrag (&bout)[CH], f32x2 alpha2)
{
    #pragma unroll
    for (int rt = 0; rt < 4; rt++) {
        f32x4 acc[CH];
        layer_mfma<DATA, CH>(sWA, sB, l, rt, q, n, bin, acc);
        pw_store<DATA, CH>(acc, bout, rt, alpha2);
        // Pin VALU/MFMA order at rt granularity (kills the r7-r10 spill hoists).
        __builtin_amdgcn_sched_barrier(SB_MASK);
    }
}

template<bool DATA, int CH>
__device__ __forceinline__ double run_mode(
    const float* __restrict__ xd, const float* __restrict__ yd,
    const float* __restrict__ xp, float alpha,
    const _Float16* sWA, const f16x8 (&a0r)[4],
    const float (*sB)[64], const float (*sW0r)[64], const float* sW4, float b4,
    int q, int n, int wstart, int wstride)
{
    const f32x4 z4 = {0.f, 0.f, 0.f, 0.f};
    const f32x2 alpha2 = splat2(2.0f * alpha);

    const int SPI = DATA ? (16 * CH) : 16;     // samples per iter
    const int NIT = NSAMP / SPI;
    double dacc = 0.0;

    // r14: pointer walks instead of per-iter index math.
    const float* px = (DATA ? xd : xp) + (size_t)(wstart * SPI + n) * 3;
    const float* py = yd + (size_t)(wstart * SPI) + n;
    const size_t xstep = (size_t)wstride * SPI * 3;
    const size_t ystep = (size_t)wstride * SPI;

    for (int it = wstart; it < NIT; it += wstride) {
        BFrag bfA[CH], bfB[CH];             // ping-pong, always constant-indexed
        // ---------------- layer 0 (K=32 padded, k<3 nonzero; A-frags in regs) ----------------
        {
            // r17: PHYS needs only the c=0 B-frag (x-values); channels 1-3
            // are hoisted to sW0r reads (one-hot-B MFMA == constant row).
            const int NBF = DATA ? CH : 1;
            f16x8 b0f[NBF];
            #pragma unroll
            for (int c = 0; c < NBF; c++) {
                union { f16x8 v; u32 dd[4]; _Float16 h[8]; } u;
                u.dd[0] = u.dd[1] = u.dd[2] = u.dd[3] = 0u;
                if (q == 0) {
                    const float* pc = px + c * 48;   // c*16 samples * 3
                    u.h[0] = (_Float16)pc[0];
                    u.h[1] = (_Float16)pc[1];
                    u.h[2] = (_Float16)pc[2];
                }
                b0f[c] = u.v;
            }
            #pragma unroll
            for (int rt = 0; rt < 4; rt++) {
                f32x4 bias = *(const f32x4*)&sB[0][rt * 16 + q * 4];
                f32x4 acc[CH];
                if (DATA) {
                    #pragma unroll
                    for (int c = 0; c < CH; c++)
                        acc[c] = __builtin_amdgcn_mfma_f32_16x16x32_f16(a0r[rt], b0f[c], bias, 0, 0, 0);
                } else {
                    acc[0] = __builtin_amdgcn_mfma_f32_16x16x32_f16(a0r[rt], b0f[0], bias, 0, 0, 0);
                    acc[1] = *(const f32x4*)&sW0r[0][rt * 16 + q * 4];
                    acc[2] = *(const f32x4*)&sW0r[1][rt * 16 + q * 4];
                    acc[3] = *(const f32x4*)&sW0r[2][rt * 16 + q * 4];
                }
                pw_store<DATA, CH>(acc, bfA, rt, alpha2);
                __builtin_amdgcn_sched_barrier(SB_MASK);
            }
        }

        // ---------------- hidden layers, manually unrolled ping-pong ----------------
        hidden_layer<DATA, CH>(sWA, sB, 0, q, n, bfA, bfB, alpha2);
        hidden_layer<DATA, CH>(sWA, sB, 1, q, n, bfB, bfA, alpha2);

        // ---------------- last hidden layer + fold 64->1 into partials ----------------
        f32x2 t2[CH];                              // DATA partials (pair accumulators)
        #pragma unroll
        for (int c = 0; c < CH; c++) t2[c] = splat2(0.f);
        f32x2 tr2 = splat2(0.f);                   // PHYS residual pair accumulator
        #pragma unroll
        for (int rt = 0; rt < 4; rt++) {
            f32x4 acc[CH];
            layer_mfma<DATA, CH>(sWA, sB, 2, rt, q, n, bfA, acc);
            f32x4 w4v = *(const f32x4*)&sW4[rt * 16 + q * 4];
            f32x2 wlo = lo2(w4v), whi = hi2(w4v);
            if (DATA) {
                #pragma unroll
                for (int c = 0; c < CH; c++) {
                    t2[c] = t2[c] + wlo * fast_tanh2(lo2(acc[c]));
                    t2[c] = t2[c] + whi * fast_tanh2(hi2(acc[c]));
                }
            } else {
                tr2 = tr2 + wlo * phys_resid(lo2(acc[0]), lo2(acc[1]), lo2(acc[2]), lo2(acc[3]), alpha2);
                tr2 = tr2 + whi * phys_resid(hi2(acc[0]), hi2(acc[1]), hi2(acc[2]), hi2(acc[3]), alpha2);
            }
        }

        // ---------------- epilogue ----------------
        if (DATA) {
            float t[CH];
            #pragma unroll
            for (int c = 0; c < CH; c++) {
                t[c] = t2[c].x + t2[c].y;
                t[c] += __shfl_xor(t[c], 16, 64);
                t[c] += __shfl_xor(t[c], 32, 64);
            }
            if (q == 0) {
                #pragma unroll
                for (int c = 0; c < CH; c++) {
                    float d = t[c] + b4 - py[c * 16];
                    dacc += (double)d * (double)d;
                }
            }
        } else {
            float tr = tr2.x + tr2.y;
            tr += __shfl_xor(tr, 16, 64);
            tr += __shfl_xor(tr, 32, 64);
            if (q == 0) dacc += (double)tr * (double)tr;
        }

        px += xstep;
        py += ystep;
    }
    return dacc;
}

// waves_per_eu(2,8): proven config (r13/r14: VGPR=60, 77us). Do NOT use a
// hard floor (r16: allocator spills to fit) or free the scheduler (r15).
__global__ __launch_bounds__(BLK)
__attribute__((amdgpu_waves_per_eu(2, 8)))
void fused_kernel(
    const float* __restrict__ xd, const float* __restrict__ yd, const float* __restrict__ xp,
    const float* __restrict__ W0, const float* __restrict__ b0,
    const float* __restrict__ W1, const float* __restrict__ b1,
    const float* __restrict__ W2, const float* __restrict__ b2,
    const float* __restrict__ W3, const float* __restrict__ b3,
    const float* __restrict__ W4, const float* __restrict__ b4,
    const float* __restrict__ log_alpha,
    double* __restrict__ accg)     // accg[2*bid+0]=phys partial, [2*bid+1]=data partial
{
    __shared__ __align__(16) _Float16 sWA[3 * 4 * 2 * 4 * 16 * 8];   // 24576 B
    __shared__ __align__(16) float sB[4][64];
    __shared__ __align__(16) float sW0r[3][64];   // r17: pre-rounded W0 rows
    __shared__ __align__(16) float sW4s[64];
    __shared__ float sb4;
    __shared__ double sRedP[NW], sRedD[NW];

    const int tid = threadIdx.x;
    // Hidden-layer A-frags with neuron relabel p(k):
    //   A_l[m][k] = W_l[p(k)][m],  p(k) = rt*16 + q*4 + r,
    //   rt = 2*(k>>5) + ((k>>2)&1), q = (k>>3)&3, r = k&3.
    // Makes the C->B layer transition lane-local (verified absmax 0.0, r5-r15).
    for (int idx = tid; idx < 3 * 4096; idx += BLK) {
        int l = idx >> 12, rem = idx & 4095, k = rem >> 6, m = rem & 63;
        const float* Ws = (l == 0) ? W1 : (l == 1) ? W2 : W3;   // [in][out]
        int pk_ = (2 * (k >> 5) + ((k >> 2) & 1)) * 16 + ((k >> 3) & 3) * 4 + (k & 3);
        int rt = m >> 4, mlo = m & 15, kt = k >> 5, qq = (k >> 3) & 3, j = k & 7;
        sWA[((((l * 4 + rt) * 2 + kt) * 4 + qq) * 16 + mlo) * 8 + j] = (_Float16)Ws[pk_ * 64 + m];
    }
    for (int i = tid; i < 64; i += BLK) {
        sB[0][i] = b0[i]; sB[1][i] = b1[i]; sB[2][i] = b2[i]; sB[3][i] = b3[i];
        sW4s[i] = W4[i];
    }
    if (tid < 192) ((float*)sW0r)[tid] = (float)(_Float16)W0[tid];
    if (tid == 0) sb4 = b4[0];

    const int wave = tid >> 6, lane = tid & 63;
    const int q = lane >> 4, n = lane & 15;
    const float alpha = __expf(log_alpha[0]);

    // layer-0 A-frags in registers (loop-invariant; only q==0 lanes non-zero).
    f16x8 a0r[4];
    #pragma unroll
    for (int rt = 0; rt < 4; rt++) {
        f16x8 v = {0, 0, 0, 0, 0, 0, 0, 0};
        if (q == 0) {
            v[0] = (_Float16)W0[0 * 64 + rt * 16 + n];
            v[1] = (_Float16)W0[1 * 64 + rt * 16 + n];
            v[2] = (_Float16)W0[2 * 64 + rt * 16 + n];
        }
        a0r[rt] = v;
    }
    __syncthreads();

    // Uniform per-wave work: 2 PHYS iters + 1 DATA2 iter, every wave.
    const int wid = blockIdx.x * NW + wave;
    double dp = run_mode<false, 4>(xd, yd, xp, alpha, sWA, a0r, sB, sW0r, sW4s, sb4,
                                   q, n, wid, TOTW);
    double dd = run_mode<true, 2>(xd, yd, xp, alpha, sWA, a0r, sB, sW0r, sW4s, sb4,
                                  q, n, wid, TOTW);
    #pragma unroll
    for (int m = 1; m < 64; m <<= 1) {
        dp = dp + shfl_xor_d(dp, m);
        dd = dd + shfl_xor_d(dd, m);
    }
    if (lane == 0) { sRedP[wave] = dp; sRedD[wave] = dd; }
    __syncthreads();
    if (tid == 0) {
        double sp = 0.0, sd = 0.0;
        #pragma unroll
        for (int w = 0; w < NW; w++) { sp += sRedP[w]; sd += sRedD[w]; }
        accg[2 * blockIdx.x + 0] = sp;
        accg[2 * blockIdx.x + 1] = sd;
    }
}

__global__ void finalize_kernel(const double* __restrict__ ws,
                                const float* __restrict__ log_lambda,
                                const float* __restrict__ log_alpha,
                                float* __restrict__ out)
{
    __shared__ double sp[256], sd[256];
    int tid = threadIdx.x;
    double pd = 0.0, dd = 0.0;
    for (int i = tid; i < GRID; i += 256) {
        pd += ws[2 * i + 0];
        dd += ws[2 * i + 1];
    }
    sp[tid] = pd; sd[tid] = dd;
    __syncthreads();
    for (int s = 128; s > 0; s >>= 1) {
        if (tid < s) { sp[tid] += sp[tid + s]; sd[tid] += sd[tid + s]; }
        __syncthreads();
    }
    if (tid == 0) {
        float pde_loss  = (float)(sp[0] / (double)NSAMP);
        float data_loss = (float)(sd[0] / (double)NSAMP);
        float alpha = expf(log_alpha[0]);
        float lam   = expf(log_lambda[0]);
        out[0] = data_loss + lam * pde_loss;
        out[1] = data_loss;
        out[2] = pde_loss;
        out[3] = alpha;
        out[4] = lam;
    }
}

extern "C" void kernel_launch(void* const* d_in, const int* in_sizes, int n_in,
                              void* d_out, int out_size, void* d_ws, size_t ws_size,
                              hipStream_t stream) {
    const float* xd = (const float*)d_in[0];
    const float* yd = (const float*)d_in[1];
    const float* xp = (const float*)d_in[2];
    const float* W0 = (const float*)d_in[3];
    const float* b0 = (const float*)d_in[4];
    const float* W1 = (const float*)d_in[5];
    const float* b1 = (const float*)d_in[6];
    const float* W2 = (const float*)d_in[7];
    const float* b2 = (const float*)d_in[8];
    const float* W3 = (const float*)d_in[9];
    const float* b3 = (const float*)d_in[10];
    const float* W4 = (const float*)d_in[11];
    const float* b4 = (const float*)d_in[12];
    const float* log_lambda = (const float*)d_in[13];
    const float* log_alpha  = (const float*)d_in[14];
    float* out = (float*)d_out;
    double* acc = (double*)d_ws;   // 2*GRID doubles of per-block partials

    fused_kernel<<<GRID, BLK, 0, stream>>>(xd, yd, xp, W0, b0, W1, b1, W2, b2, W3, b3,
                                           W4, b4, log_alpha, acc);
    finalize_kernel<<<1, 256, 0, stream>>>(acc, log_lambda, log_alpha, out);
}

// Round 9
// 146.150 us; speedup vs baseline: 2.0044x; 1.0340x over previous
//
#include <hip/hip_runtime.h>
#include <math.h>

#define NSAMP 262144
#define NW 8              // waves per block (BLK=512)
#define BLK 512
// r13: BLK=512, GRID=1024 -> 4 blocks/CU, 2048 thr/CU = HW-max 32 waves/CU.
// r15/r16 (FAILED): sched-freedom axis closed; 0x120 @ (2,8), 60 VGPR optimum.
// r17: PHYS layer-0 one-hot-B MFMAs hoisted to sW0r LDS reads (bit-exact).
// r18: WAVE-LEVEL MODE SPECIALIZATION. Waves 0-3 = PHYS (4 iters each,
//   16384/4096), waves 4-7 = DATA2 (2 iters each, 8192/4096). Wave w ->
//   SIMD w&3, so each SIMD gets 1 PHYS + 1 DATA wave per block (4+4 per
//   SIMD across 4 blocks): trans-heavy DATA phases overlap MFMA-heavy PHYS
//   phases, decorrelating the phase-locked stalls (r18 theory: 34% issue-idle
//   at max occupancy = homogeneous waves stalling in sync). Work ratio
//   PHYS:DATA = 4.0p : 3.8p per wave -- balanced within 5%.
#define GRID 1024
#define HALFW 4096        // waves per mode

// sched_barrier mask: DS/VMEM reads may cross; VALU/MFMA/DS-writes pinned.
#define SB_MASK 0x120

typedef _Float16 f16x8 __attribute__((ext_vector_type(8)));
typedef __fp16   fp16x2 __attribute__((ext_vector_type(2)));
typedef float    f32x4 __attribute__((ext_vector_type(4)));
typedef float    f32x2 __attribute__((ext_vector_type(2)));
typedef unsigned int u32;

// PHYS channels = {0:val, 1:d/dx, 2:d/dy, 3:combo z* = z_t - alpha*(z_xx+z_yy)}
// combo closed under propagation: h* = ap*z* - alpha*app*(z1^2+z2^2); residual = W4^T h*.
// DATA channels = independent 16-sample groups (CH=2).
#define PCH 4

#define TWO_LOG2E 2.8853900817779268f   // 2*log2(e): expf(2x) = exp2(x*TWO_LOG2E)

// B-fragment as raw dwords: cvt_pkrtz output dwords are written straight into
// d[] with constant indices -> pure register naming, no f16 element inserts.
union BFrag { f16x8 v[2]; u32 d[8]; };

__device__ __forceinline__ f32x2 lo2(f32x4 v) { return __builtin_shufflevector(v, v, 0, 1); }
__device__ __forceinline__ f32x2 hi2(f32x4 v) { return __builtin_shufflevector(v, v, 2, 3); }
__device__ __forceinline__ f32x2 splat2(float s) { f32x2 v; v.x = s; v.y = s; return v; }

__device__ __forceinline__ u32 pkdw(f32x2 p) {
    union { fp16x2 h; u32 u; } c;
    c.h = __builtin_amdgcn_cvt_pkrtz(p.x, p.y);
    return c.u;
}

// pair tanh (r13: trans pipe has slack; full-rate VALU is binding -> keep the
// minimal 3-full-rate/4-trans form, do NOT rcp-pair).
__device__ __forceinline__ f32x2 fast_tanh2(f32x2 x) {
    f32x2 t = x * splat2(TWO_LOG2E);
    f32x2 e;
    e.x = __builtin_amdgcn_exp2f(t.x);
    e.y = __builtin_amdgcn_exp2f(t.y);
    f32x2 d = e + splat2(1.0f);
    f32x2 rc;
    rc.x = __builtin_amdgcn_rcpf(d.x);
    rc.y = __builtin_amdgcn_rcpf(d.y);
    return splat2(1.0f) - splat2(2.0f) * rc;
}

// PHYS pointwise on an r-pair: z* channels in, h* channels out (packed math).
__device__ __forceinline__ void phys_half(f32x2 z0, f32x2 z1, f32x2 z2, f32x2 z3,
                                          f32x2 alpha2, f32x2 (&h)[PCH])
{
    f32x2 a    = fast_tanh2(z0);
    f32x2 ap   = splat2(1.0f) - a * a;
    f32x2 napp = (a * ap) * alpha2;          // = -alpha*app = 2*alpha*a*ap
    h[0] = a;
    h[1] = ap * z1;
    h[2] = ap * z2;
    f32x2 s = z1 * z1 + z2 * z2;
    h[3] = ap * z3 + napp * s;
}

// Final-fold variant: only h[3] is consumed (r14: drops h1/h2 products).
// h3 math is op-for-op identical to phys_half's h[3].
__device__ __forceinline__ f32x2 phys_resid(f32x2 z0, f32x2 z1, f32x2 z2, f32x2 z3,
                                            f32x2 alpha2)
{
    f32x2 a    = fast_tanh2(z0);
    f32x2 ap   = splat2(1.0f) - a * a;
    f32x2 napp = (a * ap) * alpha2;
    f32x2 s = z1 * z1 + z2 * z2;
    return ap * z3 + napp * s;
}

__device__ __forceinline__ double shfl_xor_d(double v, int m) {
    union { double d; int i[2]; } u; u.d = v;
    u.i[0] = __shfl_xor(u.i[0], m, 64);
    u.i[1] = __shfl_xor(u.i[1], m, 64);
    return u.d;
}

// pointwise on one rt's acc[CH] -> two dwords per channel, written in place.
template<bool DATA, int CH>
__device__ __forceinline__ void pw_store(const f32x4* acc, BFrag (&bout)[CH],
                                         int rt, f32x2 alpha2)
{
    if constexpr (DATA) {
        #pragma unroll
        for (int c = 0; c < CH; c++) {
            bout[c].d[rt * 2 + 0] = pkdw(fast_tanh2(lo2(acc[c])));
            bout[c].d[rt * 2 + 1] = pkdw(fast_tanh2(hi2(acc[c])));
        }
    } else {
        f32x2 hlo[PCH], hhi[PCH];
        phys_half(lo2(acc[0]), lo2(acc[1]), lo2(acc[2]), lo2(acc[3]), alpha2, hlo);
        phys_half(hi2(acc[0]), hi2(acc[1]), hi2(acc[2]), hi2(acc[3]), alpha2, hhi);
        #pragma unroll
        for (int c = 0; c < CH; c++) {
            bout[c].d[rt * 2 + 0] = pkdw(hlo[c]);
            bout[c].d[rt * 2 + 1] = pkdw(hhi[c]);
        }
    }
}

template<bool DATA, int CH>
__device__ __forceinline__ void layer_mfma(
    const _Float16* sWA, const float (*sB)[64],
    int l, int rt, int q, int n, const BFrag (&bf)[CH], f32x4 (&acc)[CH])
{
    const f32x4 z4 = {0.f, 0.f, 0.f, 0.f};
    f16x8 a0k = *(const f16x8*)&sWA[((((l * 4 + rt) * 2 + 0) * 4 + q) * 16 + n) * 8];
    f16x8 a1k = *(const f16x8*)&sWA[((((l * 4 + rt) * 2 + 1) * 4 + q) * 16 + n) * 8];
    f32x4 bias = *(const f32x4*)&sB[l + 1][rt * 16 + q * 4];
    #pragma unroll
    for (int c = 0; c < CH; c++) {
        f32x4 cin = (DATA || c == 0) ? bias : z4;
        acc[c] = __builtin_amdgcn_mfma_f32_16x16x32_f16(a0k, bf[c].v[0], cin, 0, 0, 0);
        acc[c] = __builtin_amdgcn_mfma_f32_16x16x32_f16(a1k, bf[c].v[1], acc[c], 0, 0, 0);
    }
}

template<bool DATA, int CH>
__device__ __forceinline__ void hidden_layer(
    const _Float16* sWA, const float (*sB)[64],
    int l, int q, int n, const BFrag (&bin)[CH], BFrag (&bout)[CH], f32x2 alpha2)
{
    #pragma unroll
    for (int rt = 0; rt < 4; rt++) {
        f32x4 acc[CH];
        layer_mfma<DATA, CH>(sWA, sB, l, rt, q, n, bin, acc);
        pw_store<DATA, CH>(acc, bout, rt, alpha2);
        // Pin VALU/MFMA order at rt granularity (kills the r7-r10 spill hoists).
        __builtin_amdgcn_sched_barrier(SB_MASK);
    }
}

template<bool DATA, int CH>
__device__ __forceinline__ double run_mode(
    const float* __restrict__ xd, const float* __restrict__ yd,
    const float* __restrict__ xp, float alpha,
    const _Float16* sWA, const f16x8 (&a0r)[4],
    const float (*sB)[64], const float (*sW0r)[64], const float* sW4, float b4,
    int q, int n, int wstart, int wstride)
{
    const f32x4 z4 = {0.f, 0.f, 0.f, 0.f};
    const f32x2 alpha2 = splat2(2.0f * alpha);

    const int SPI = DATA ? (16 * CH) : 16;     // samples per iter
    const int NIT = NSAMP / SPI;
    double dacc = 0.0;

    // r14: pointer walks instead of per-iter index math.
    const float* px = (DATA ? xd : xp) + (size_t)(wstart * SPI + n) * 3;
    const float* py = yd + (size_t)(wstart * SPI) + n;
    const size_t xstep = (size_t)wstride * SPI * 3;
    const size_t ystep = (size_t)wstride * SPI;

    for (int it = wstart; it < NIT; it += wstride) {
        BFrag bfA[CH], bfB[CH];             // ping-pong, always constant-indexed
        // ---------------- layer 0 (K=32 padded, k<3 nonzero; A-frags in regs) ----------------
        {
            // r17: PHYS needs only the c=0 B-frag (x-values); channels 1-3
            // are hoisted to sW0r reads (one-hot-B MFMA == constant row).
            const int NBF = DATA ? CH : 1;
            f16x8 b0f[NBF];
            #pragma unroll
            for (int c = 0; c < NBF; c++) {
                union { f16x8 v; u32 dd[4]; _Float16 h[8]; } u;
                u.dd[0] = u.dd[1] = u.dd[2] = u.dd[3] = 0u;
                if (q == 0) {
                    const float* pc = px + c * 48;   // c*16 samples * 3
                    u.h[0] = (_Float16)pc[0];
                    u.h[1] = (_Float16)pc[1];
                    u.h[2] = (_Float16)pc[2];
                }
                b0f[c] = u.v;
            }
            #pragma unroll
            for (int rt = 0; rt < 4; rt++) {
                f32x4 bias = *(const f32x4*)&sB[0][rt * 16 + q * 4];
                f32x4 acc[CH];
                if (DATA) {
                    #pragma unroll
                    for (int c = 0; c < CH; c++)
                        acc[c] = __builtin_amdgcn_mfma_f32_16x16x32_f16(a0r[rt], b0f[c], bias, 0, 0, 0);
                } else {
                    acc[0] = __builtin_amdgcn_mfma_f32_16x16x32_f16(a0r[rt], b0f[0], bias, 0, 0, 0);
                    acc[1] = *(const f32x4*)&sW0r[0][rt * 16 + q * 4];
                    acc[2] = *(const f32x4*)&sW0r[1][rt * 16 + q * 4];
                    acc[3] = *(const f32x4*)&sW0r[2][rt * 16 + q * 4];
                }
                pw_store<DATA, CH>(acc, bfA, rt, alpha2);
                __builtin_amdgcn_sched_barrier(SB_MASK);
            }
        }

        // ---------------- hidden layers, manually unrolled ping-pong ----------------
        hidden_layer<DATA, CH>(sWA, sB, 0, q, n, bfA, bfB, alpha2);
        hidden_layer<DATA, CH>(sWA, sB, 1, q, n, bfB, bfA, alpha2);

        // ---------------- last hidden layer + fold 64->1 into partials ----------------
        f32x2 t2[CH];                              // DATA partials (pair accumulators)
        #pragma unroll
        for (int c = 0; c < CH; c++) t2[c] = splat2(0.f);
        f32x2 tr2 = splat2(0.f);                   // PHYS residual pair accumulator
        #pragma unroll
        for (int rt = 0; rt < 4; rt++) {
            f32x4 acc[CH];
            layer_mfma<DATA, CH>(sWA, sB, 2, rt, q, n, bfA, acc);
            f32x4 w4v = *(const f32x4*)&sW4[rt * 16 + q * 4];
            f32x2 wlo = lo2(w4v), whi = hi2(w4v);
            if (DATA) {
                #pragma unroll
                for (int c = 0; c < CH; c++) {
                    t2[c] = t2[c] + wlo * fast_tanh2(lo2(acc[c]));
                    t2[c] = t2[c] + whi * fast_tanh2(hi2(acc[c]));
                }
            } else {
                tr2 = tr2 + wlo * phys_resid(lo2(acc[0]), lo2(acc[1]), lo2(acc[2]), lo2(acc[3]), alpha2);
                tr2 = tr2 + whi * phys_resid(hi2(acc[0]), hi2(acc[1]), hi2(acc[2]), hi2(acc[3]), alpha2);
            }
        }

        // ---------------- epilogue ----------------
        if (DATA) {
            float t[CH];
            #pragma unroll
            for (int c = 0; c < CH; c++) {
                t[c] = t2[c].x + t2[c].y;
                t[c] += __shfl_xor(t[c], 16, 64);
                t[c] += __shfl_xor(t[c], 32, 64);
            }
            if (q == 0) {
                #pragma unroll
                for (int c = 0; c < CH; c++) {
                    float d = t[c] + b4 - py[c * 16];
                    dacc += (double)d * (double)d;
                }
            }
        } else {
            float tr = tr2.x + tr2.y;
            tr += __shfl_xor(tr, 16, 64);
            tr += __shfl_xor(tr, 32, 64);
            if (q == 0) dacc += (double)tr * (double)tr;
        }

        px += xstep;
        py += ystep;
    }
    return dacc;
}

// waves_per_eu(2,8): proven config (r13-r17: VGPR=60, zero spill). Do NOT use
// a hard floor (r16: allocator spills to fit) or free the scheduler (r15).
__global__ __launch_bounds__(BLK)
__attribute__((amdgpu_waves_per_eu(2, 8)))
void fused_kernel(
    const float* __restrict__ xd, const float* __restrict__ yd, const float* __restrict__ xp,
    const float* __restrict__ W0, const float* __restrict__ b0,
    const float* __restrict__ W1, const float* __restrict__ b1,
    const float* __restrict__ W2, const float* __restrict__ b2,
    const float* __restrict__ W3, const float* __restrict__ b3,
    const float* __restrict__ W4, const float* __restrict__ b4,
    const float* __restrict__ log_alpha,
    double* __restrict__ accg)     // accg[2*bid+0]=phys partial, [2*bid+1]=data partial
{
    __shared__ __align__(16) _Float16 sWA[3 * 4 * 2 * 4 * 16 * 8];   // 24576 B
    __shared__ __align__(16) float sB[4][64];
    __shared__ __align__(16) float sW0r[3][64];   // r17: pre-rounded W0 rows
    __shared__ __align__(16) float sW4s[64];
    __shared__ float sb4;
    __shared__ double sRedP[4], sRedD[4];

    const int tid = threadIdx.x;
    // Hidden-layer A-frags with neuron relabel p(k):
    //   A_l[m][k] = W_l[p(k)][m],  p(k) = rt*16 + q*4 + r,
    //   rt = 2*(k>>5) + ((k>>2)&1), q = (k>>3)&3, r = k&3.
    // Makes the C->B layer transition lane-local (verified absmax 0.0, r5-r17).
    for (int idx = tid; idx < 3 * 4096; idx += BLK) {
        int l = idx >> 12, rem = idx & 4095, k = rem >> 6, m = rem & 63;
        const float* Ws = (l == 0) ? W1 : (l == 1) ? W2 : W3;   // [in][out]
        int pk_ = (2 * (k >> 5) + ((k >> 2) & 1)) * 16 + ((k >> 3) & 3) * 4 + (k & 3);
        int rt = m >> 4, mlo = m & 15, kt = k >> 5, qq = (k >> 3) & 3, j = k & 7;
        sWA[((((l * 4 + rt) * 2 + kt) * 4 + qq) * 16 + mlo) * 8 + j] = (_Float16)Ws[pk_ * 64 + m];
    }
    for (int i = tid; i < 64; i += BLK) {
        sB[0][i] = b0[i]; sB[1][i] = b1[i]; sB[2][i] = b2[i]; sB[3][i] = b3[i];
        sW4s[i] = W4[i];
    }
    if (tid < 192) ((float*)sW0r)[tid] = (float)(_Float16)W0[tid];
    if (tid == 0) sb4 = b4[0];

    const int wave = tid >> 6, lane = tid & 63;
    const int q = lane >> 4, n = lane & 15;
    const float alpha = __expf(log_alpha[0]);

    // layer-0 A-frags in registers (loop-invariant; only q==0 lanes non-zero).
    f16x8 a0r[4];
    #pragma unroll
    for (int rt = 0; rt < 4; rt++) {
        f16x8 v = {0, 0, 0, 0, 0, 0, 0, 0};
        if (q == 0) {
            v[0] = (_Float16)W0[0 * 64 + rt * 16 + n];
            v[1] = (_Float16)W0[1 * 64 + rt * 16 + n];
            v[2] = (_Float16)W0[2 * 64 + rt * 16 + n];
        }
        a0r[rt] = v;
    }
    __syncthreads();

    // r18: wave-level mode split. Waves 0-3 PHYS (4 iters), 4-7 DATA2 (2 iters).
    // Wave w -> SIMD w&3, so each SIMD hosts 1 PHYS + 1 DATA wave per block.
    double dacc;
    if (wave < 4) {
        dacc = run_mode<false, 4>(xd, yd, xp, alpha, sWA, a0r, sB, sW0r, sW4s, sb4,
                                  q, n, blockIdx.x * 4 + wave, HALFW);
    } else {
        dacc = run_mode<true, 2>(xd, yd, xp, alpha, sWA, a0r, sB, sW0r, sW4s, sb4,
                                 q, n, blockIdx.x * 4 + (wave - 4), HALFW);
    }
    #pragma unroll
    for (int m = 1; m < 64; m <<= 1) dacc = dacc + shfl_xor_d(dacc, m);
    if (lane == 0) {
        if (wave < 4) sRedP[wave] = dacc;
        else          sRedD[wave - 4] = dacc;
    }
    __syncthreads();
    if (tid == 0)
        accg[2 * blockIdx.x + 0] = sRedP[0] + sRedP[1] + sRedP[2] + sRedP[3];
    if (tid == 64)
        accg[2 * blockIdx.x + 1] = sRedD[0] + sRedD[1] + sRedD[2] + sRedD[3];
}

__global__ void finalize_kernel(const double* __restrict__ ws,
                                const float* __restrict__ log_lambda,
                                const float* __restrict__ log_alpha,
                                float* __restrict__ out)
{
    __shared__ double sp[256], sd[256];
    int tid = threadIdx.x;
    double pd = 0.0, dd = 0.0;
    for (int i = tid; i < GRID; i += 256) {
        pd += ws[2 * i + 0];
        dd += ws[2 * i + 1];
    }
    sp[tid] = pd; sd[tid] = dd;
    __syncthreads();
    for (int s = 128; s > 0; s >>= 1) {
        if (tid < s) { sp[tid] += sp[tid + s]; sd[tid] += sd[tid + s]; }
        __syncthreads();
    }
    if (tid == 0) {
        float pde_loss  = (float)(sp[0] / (double)NSAMP);
        float data_loss = (float)(sd[0] / (double)NSAMP);
        float alpha = expf(log_alpha[0]);
        float lam   = expf(log_lambda[0]);
        out[0] = data_loss + lam * pde_loss;
        out[1] = data_loss;
        out[2] = pde_loss;
        out[3] = alpha;
        out[4] = lam;
    }
}

extern "C" void kernel_launch(void* const* d_in, const int* in_sizes, int n_in,
                              void* d_out, int out_size, void* d_ws, size_t ws_size,
                              hipStream_t stream) {
    const float* xd = (const float*)d_in[0];
    const float* yd = (const float*)d_in[1];
    const float* xp = (const float*)d_in[2];
    const float* W0 = (const float*)d_in[3];
    const float* b0 = (const float*)d_in[4];
    const float* W1 = (const float*)d_in[5];
    const float* b1 = (const float*)d_in[6];
    const float* W2 = (const float*)d_in[7];
    const float* b2 = (const float*)d_in[8];
    const float* W3 = (const float*)d_in[9];
    const float* b3 = (const float*)d_in[10];
    const float* W4 = (const float*)d_in[11];
    const float* b4 = (const float*)d_in[12];
    const float* log_lambda = (const float*)d_in[13];
    const float* log_alpha  = (const float*)d_in[14];
    float* out = (float*)d_out;
    double* acc = (double*)d_ws;   // 2*GRID doubles of per-block partials

    fused_kernel<<<GRID, BLK, 0, stream>>>(xd, yd, xp, W0, b0, W1, b1, W2, b2, W3, b3,
                                           W4, b4, log_alpha, acc);
    finalize_kernel<<<1, 256, 0, stream>>>(acc, log_lambda, log_alpha, out);
}

// Round 11
// 144.594 us; speedup vs baseline: 2.0259x; 1.0108x over previous
//
#include <hip/hip_runtime.h>
#include <math.h>

#define NSAMP 262144
#define NW 8              // waves per block (BLK=512)
#define BLK 512
// r13: BLK=512, GRID=1024 -> 4 blocks/CU, 2048 thr/CU = HW-max 32 waves/CU.
// r15/r16 (FAILED): sched-freedom axis closed; 0x120 @ (2,8) optimum.
// r17: PHYS layer-0 one-hot-B MFMAs hoisted to sW0r LDS reads (bit-exact).
// r18: wave-level mode split (waves 0-3 PHYS x4 iters, 4-7 DATA2 x2 iters),
//   wave w -> SIMD w&3 mixes 1 PHYS + 1 DATA per SIMD per block (75.8->73).
// r19: INPUT PREFETCH PIPELINE. FETCH=3.9MB at 53GB/s = latency-bound input
//   reads: every iter's layer-0 x-load (and DATA epilogue y-load) is an
//   exposed ~900cy HBM miss consumed immediately; all waves hit it in sync
//   -> the ~30% no-issue fraction. Fix: load iter j+1's x/y at the top of
//   iter j (VMEM_READ crosses the 0x120 sched_barrier), consume from regs.
//   VGPR headroom for the in-flight values: a0r[4] (16 VGPR, loop-invariant,
//   wave-uniform) moved to LDS sA0 (4KB, +4 ds_read_b128/iter on a ~35%-busy
//   DS pipe). Last-iter prefetch pointer clamped in-bounds.
#define GRID 1024
#define HALFW 4096        // waves per mode

// sched_barrier mask: DS/VMEM reads may cross; VALU/MFMA/DS-writes pinned.
#define SB_MASK 0x120

typedef _Float16 f16x8 __attribute__((ext_vector_type(8)));
typedef __fp16   fp16x2 __attribute__((ext_vector_type(2)));
typedef float    f32x4 __attribute__((ext_vector_type(4)));
typedef float    f32x2 __attribute__((ext_vector_type(2)));
typedef unsigned int u32;

// PHYS channels = {0:val, 1:d/dx, 2:d/dy, 3:combo z* = z_t - alpha*(z_xx+z_yy)}
// combo closed under propagation: h* = ap*z* - alpha*app*(z1^2+z2^2); residual = W4^T h*.
// DATA channels = independent 16-sample groups (CH=2).
#define PCH 4

#define TWO_LOG2E 2.8853900817779268f   // 2*log2(e): expf(2x) = exp2(x*TWO_LOG2E)

// B-fragment as raw dwords: cvt_pkrtz output dwords are written straight into
// d[] with constant indices -> pure register naming, no f16 element inserts.
union BFrag { f16x8 v[2]; u32 d[8]; };

__device__ __forceinline__ f32x2 lo2(f32x4 v) { return __builtin_shufflevector(v, v, 0, 1); }
__device__ __forceinline__ f32x2 hi2(f32x4 v) { return __builtin_shufflevector(v, v, 2, 3); }
__device__ __forceinline__ f32x2 splat2(float s) { f32x2 v; v.x = s; v.y = s; return v; }

__device__ __forceinline__ u32 pkdw(f32x2 p) {
    union { fp16x2 h; u32 u; } c;
    c.h = __builtin_amdgcn_cvt_pkrtz(p.x, p.y);
    return c.u;
}

// pair tanh (r13: trans pipe has slack; full-rate VALU is binding -> keep the
// minimal 3-full-rate/4-trans form, do NOT rcp-pair).
__device__ __forceinline__ f32x2 fast_tanh2(f32x2 x) {
    f32x2 t = x * splat2(TWO_LOG2E);
    f32x2 e;
    e.x = __builtin_amdgcn_exp2f(t.x);
    e.y = __builtin_amdgcn_exp2f(t.y);
    f32x2 d = e + splat2(1.0f);
    f32x2 rc;
    rc.x = __builtin_amdgcn_rcpf(d.x);
    rc.y = __builtin_amdgcn_rcpf(d.y);
    return splat2(1.0f) - splat2(2.0f) * rc;
}

// PHYS pointwise on an r-pair: z* channels in, h* channels out (packed math).
__device__ __forceinline__ void phys_half(f32x2 z0, f32x2 z1, f32x2 z2, f32x2 z3,
                                          f32x2 alpha2, f32x2 (&h)[PCH])
{
    f32x2 a    = fast_tanh2(z0);
    f32x2 ap   = splat2(1.0f) - a * a;
    f32x2 napp = (a * ap) * alpha2;          // = -alpha*app = 2*alpha*a*ap
    h[0] = a;
    h[1] = ap * z1;
    h[2] = ap * z2;
    f32x2 s = z1 * z1 + z2 * z2;
    h[3] = ap * z3 + napp * s;
}

// Final-fold variant: only h[3] is consumed (r14: drops h1/h2 products).
// h3 math is op-for-op identical to phys_half's h[3].
__device__ __forceinline__ f32x2 phys_resid(f32x2 z0, f32x2 z1, f32x2 z2, f32x2 z3,
                                            f32x2 alpha2)
{
    f32x2 a    = fast_tanh2(z0);
    f32x2 ap   = splat2(1.0f) - a * a;
    f32x2 napp = (a * ap) * alpha2;
    f32x2 s = z1 * z1 + z2 * z2;
    return ap * z3 + napp * s;
}

__device__ __forceinline__ double shfl_xor_d(double v, int m) {
    union { double d; int i[2]; } u; u.d = v;
    u.i[0] = __shfl_xor(u.i[0], m, 64);
    u.i[1] = __shfl_xor(u.i[1], m, 64);
    return u.d;
}

// pointwise on one rt's acc[CH] -> two dwords per channel, written in place.
template<bool DATA, int CH>
__device__ __forceinline__ void pw_store(const f32x4* acc, BFrag (&bout)[CH],
                                         int rt, f32x2 alpha2)
{
    if constexpr (DATA) {
        #pragma unroll
        for (int c = 0; c < CH; c++) {
            bout[c].d[rt * 2 + 0] = pkdw(fast_tanh2(lo2(acc[c])));
            bout[c].d[rt * 2 + 1] = pkdw(fast_tanh2(hi2(acc[c])));
        }
    } else {
        f32x2 hlo[PCH], hhi[PCH];
        phys_half(lo2(acc[0]), lo2(acc[1]), lo2(acc[2]), lo2(acc[3]), alpha2, hlo);
        phys_half(hi2(acc[0]), hi2(acc[1]), hi2(acc[2]), hi2(acc[3]), alpha2, hhi);
        #pragma unroll
        for (int c = 0; c < CH; c++) {
            bout[c].d[rt * 2 + 0] = pkdw(hlo[c]);
            bout[c].d[rt * 2 + 1] = pkdw(hhi[c]);
        }
    }
}

template<bool DATA, int CH>
__device__ __forceinline__ void layer_mfma(
    const _Float16* sWA, const float (*sB)[64],
    int l, int rt, int q, int n, const BFrag (&bf)[CH], f32x4 (&acc)[CH])
{
    const f32x4 z4 = {0.f, 0.f, 0.f, 0.f};
    f16x8 a0k = *(const f16x8*)&sWA[((((l * 4 + rt) * 2 + 0) * 4 + q) * 16 + n) * 8];
    f16x8 a1k = *(const f16x8*)&sWA[((((l * 4 + rt) * 2 + 1) * 4 + q) * 16 + n) * 8];
    f32x4 bias = *(const f32x4*)&sB[l + 1][rt * 16 + q * 4];
    #pragma unroll
    for (int c = 0; c < CH; c++) {
        f32x4 cin = (DATA || c == 0) ? bias : z4;
        acc[c] = __builtin_amdgcn_mfma_f32_16x16x32_f16(a0k, bf[c].v[0], cin, 0, 0, 0);
        acc[c] = __builtin_amdgcn_mfma_f32_16x16x32_f16(a1k, bf[c].v[1], acc[c], 0, 0, 0);
    }
}

template<bool DATA, int CH>
__device__ __forceinline__ void hidden_layer(
    const _Float16* sWA, const float (*sB)[64],
    int l, int q, int n, const BFrag (&bin)[CH], BFrag (&bout)[CH], f32x2 alpha2)
{
    #pragma unroll
    for (int rt = 0; rt < 4; rt++) {
        f32x4 acc[CH];
        layer_mfma<DATA, CH>(sWA, sB, l, rt, q, n, bin, acc);
        pw_store<DATA, CH>(acc, bout, rt, alpha2);
        // Pin VALU/MFMA order at rt granularity (kills the r7-r10 spill hoists).
        __builtin_amdgcn_sched_barrier(SB_MASK);
    }
}

template<bool DATA, int CH>
__device__ __forceinline__ double run_mode(
    const float* __restrict__ xd, const float* __restrict__ yd,
    const float* __restrict__ xp, float alpha,
    const _Float16* sWA, const _Float16* sA0,
    const float (*sB)[64], const float (*sW0r)[64], const float* sW4, float b4,
    int q, int n, int lane, int wstart)
{
    const f32x4 z4 = {0.f, 0.f, 0.f, 0.f};
    const f32x2 alpha2 = splat2(2.0f * alpha);

    constexpr int SPI   = DATA ? (16 * CH) : 16;     // samples per iter
    constexpr int ITERS = (NSAMP / SPI) / HALFW;     // PHYS: 4, DATA2: 2
    constexpr int NBF   = DATA ? CH : 1;             // x-load groups
    constexpr int NY    = DATA ? CH : 1;             // y values (PHYS unused)
    double dacc = 0.0;

    const float* px = (DATA ? xd : xp) + (size_t)(wstart * SPI + n) * 3;
    const float* py = yd + (size_t)(wstart * SPI) + n;
    const size_t xstep = (size_t)HALFW * SPI * 3;
    const size_t ystep = (size_t)HALFW * SPI;

    // r19 prologue: load iter-0 inputs (q==0 lanes carry layer-0 B data).
    float cx[NBF][3];
    float cyv[NY];
    if (q == 0) {
        #pragma unroll
        for (int c = 0; c < NBF; c++) {
            cx[c][0] = px[c * 48 + 0];
            cx[c][1] = px[c * 48 + 1];
            cx[c][2] = px[c * 48 + 2];
        }
        if (DATA) {
            #pragma unroll
            for (int c = 0; c < NY; c++) cyv[c] = py[c * 16];
        }
    }

    #pragma unroll 1
    for (int j = 0; j < ITERS; ++j) {
        // ---- r19: issue NEXT-iter loads now; ~900cy HBM latency hides under
        // this iteration's compute (VMEM_READ crosses the sched_barriers).
        const float* pxn = (j + 1 < ITERS) ? px + xstep : px;   // in-bounds clamp
        const float* pyn = (j + 1 < ITERS) ? py + ystep : py;
        float nx[NBF][3];
        float nyv[NY];
        if (q == 0) {
            #pragma unroll
            for (int c = 0; c < NBF; c++) {
                nx[c][0] = pxn[c * 48 + 0];
                nx[c][1] = pxn[c * 48 + 1];
                nx[c][2] = pxn[c * 48 + 2];
            }
            if (DATA) {
                #pragma unroll
                for (int c = 0; c < NY; c++) nyv[c] = pyn[c * 16];
            }
        }

        BFrag bfA[CH], bfB[CH];             // ping-pong, always constant-indexed
        // ---------------- layer 0 (K=32 padded, k<3 nonzero; A-frags in sA0) ----------------
        {
            // r17: PHYS needs only the c=0 B-frag; channels 1-3 hoisted to sW0r.
            f16x8 b0f[NBF];
            #pragma unroll
            for (int c = 0; c < NBF; c++) {
                union { f16x8 v; u32 dd[4]; _Float16 h[8]; } u;
                u.dd[0] = u.dd[1] = u.dd[2] = u.dd[3] = 0u;
                if (q == 0) {
                    u.h[0] = (_Float16)cx[c][0];
                    u.h[1] = (_Float16)cx[c][1];
                    u.h[2] = (_Float16)cx[c][2];
                }
                b0f[c] = u.v;
            }
            #pragma unroll
            for (int rt = 0; rt < 4; rt++) {
                f16x8 a0 = *(const f16x8*)&sA0[(rt * 64 + lane) * 8];   // r19: was a0r[rt]
                f32x4 bias = *(const f32x4*)&sB[0][rt * 16 + q * 4];
                f32x4 acc[CH];
                if (DATA) {
                    #pragma unroll
                    for (int c = 0; c < CH; c++)
                        acc[c] = __builtin_amdgcn_mfma_f32_16x16x32_f16(a0, b0f[c], bias, 0, 0, 0);
                } else {
                    acc[0] = __builtin_amdgcn_mfma_f32_16x16x32_f16(a0, b0f[0], bias, 0, 0, 0);
                    acc[1] = *(const f32x4*)&sW0r[0][rt * 16 + q * 4];
                    acc[2] = *(const f32x4*)&sW0r[1][rt * 16 + q * 4];
                    acc[3] = *(const f32x4*)&sW0r[2][rt * 16 + q * 4];
                }
                pw_store<DATA, CH>(acc, bfA, rt, alpha2);
                __builtin_amdgcn_sched_barrier(SB_MASK);
            }
        }

        // ---------------- hidden layers, manually unrolled ping-pong ----------------
        hidden_layer<DATA, CH>(sWA, sB, 0, q, n, bfA, bfB, alpha2);
        hidden_layer<DATA, CH>(sWA, sB, 1, q, n, bfB, bfA, alpha2);

        // ---------------- last hidden layer + fold 64->1 into partials ----------------
        f32x2 t2[CH];                              // DATA partials (pair accumulators)
        #pragma unroll
        for (int c = 0; c < CH; c++) t2[c] = splat2(0.f);
        f32x2 tr2 = splat2(0.f);                   // PHYS residual pair accumulator
        #pragma unroll
        for (int rt = 0; rt < 4; rt++) {
            f32x4 acc[CH];
            layer_mfma<DATA, CH>(sWA, sB, 2, rt, q, n, bfA, acc);
            f32x4 w4v = *(const f32x4*)&sW4[rt * 16 + q * 4];
            f32x2 wlo = lo2(w4v), whi = hi2(w4v);
            if (DATA) {
                #pragma unroll
                for (int c = 0; c < CH; c++) {
                    t2[c] = t2[c] + wlo * fast_tanh2(lo2(acc[c]));
                    t2[c] = t2[c] + whi * fast_tanh2(hi2(acc[c]));
                }
            } else {
                tr2 = tr2 + wlo * phys_resid(lo2(acc[0]), lo2(acc[1]), lo2(acc[2]), lo2(acc[3]), alpha2);
                tr2 = tr2 + whi * phys_resid(hi2(acc[0]), hi2(acc[1]), hi2(acc[2]), hi2(acc[3]), alpha2);
            }
        }

        // ---------------- epilogue (y from prefetched regs) ----------------
        if (DATA) {
            float t[CH];
            #pragma unroll
            for (int c = 0; c < CH; c++) {
                t[c] = t2[c].x + t2[c].y;
                t[c] += __shfl_xor(t[c], 16, 64);
                t[c] += __shfl_xor(t[c], 32, 64);
            }
            if (q == 0) {
                #pragma unroll
                for (int c = 0; c < CH; c++) {
                    float d = t[c] + b4 - cyv[c];
                    dacc += (double)d * (double)d;
                }
            }
        } else {
            float tr = tr2.x + tr2.y;
            tr += __shfl_xor(tr, 16, 64);
            tr += __shfl_xor(tr, 32, 64);
            if (q == 0) dacc += (double)tr * (double)tr;
        }

        // ---- rotate prefetched inputs ----
        #pragma unroll
        for (int c = 0; c < NBF; c++) {
            cx[c][0] = nx[c][0]; cx[c][1] = nx[c][1]; cx[c][2] = nx[c][2];
        }
        if (DATA) {
            #pragma unroll
            for (int c = 0; c < NY; c++) cyv[c] = nyv[c];
        }
        px = pxn;
        py = pyn;
    }
    return dacc;
}

// waves_per_eu(2,8): proven config (r13-r18: zero spill). Do NOT use a hard
// floor (r16: allocator spills to fit) or free the scheduler (r15).
__global__ __launch_bounds__(BLK)
__attribute__((amdgpu_waves_per_eu(2, 8)))
void fused_kernel(
    const float* __restrict__ xd, const float* __restrict__ yd, const float* __restrict__ xp,
    const float* __restrict__ W0, const float* __restrict__ b0,
    const float* __restrict__ W1, const float* __restrict__ b1,
    const float* __restrict__ W2, const float* __restrict__ b2,
    const float* __restrict__ W3, const float* __restrict__ b3,
    const float* __restrict__ W4, const float* __restrict__ b4,
    const float* __restrict__ log_alpha,
    double* __restrict__ accg)     // accg[2*bid+0]=phys partial, [2*bid+1]=data partial
{
    __shared__ __align__(16) _Float16 sWA[3 * 4 * 2 * 4 * 16 * 8];   // 24576 B
    __shared__ __align__(16) _Float16 sA0[4 * 64 * 8];               // 4096 B (r19)
    __shared__ __align__(16) float sB[4][64];
    __shared__ __align__(16) float sW0r[3][64];   // r17: pre-rounded W0 rows
    __shared__ __align__(16) float sW4s[64];
    __shared__ float sb4;
    __shared__ double sRedP[4], sRedD[4];

    const int tid = threadIdx.x;
    // Hidden-layer A-frags with neuron relabel p(k):
    //   A_l[m][k] = W_l[p(k)][m],  p(k) = rt*16 + q*4 + r,
    //   rt = 2*(k>>5) + ((k>>2)&1), q = (k>>3)&3, r = k&3.
    // Makes the C->B layer transition lane-local (verified absmax 0.0, r5-r18).
    for (int idx = tid; idx < 3 * 4096; idx += BLK) {
        int l = idx >> 12, rem = idx & 4095, k = rem >> 6, m = rem & 63;
        const float* Ws = (l == 0) ? W1 : (l == 1) ? W2 : W3;   // [in][out]
        int pk_ = (2 * (k >> 5) + ((k >> 2) & 1)) * 16 + ((k >> 3) & 3) * 4 + (k & 3);
        int rt = m >> 4, mlo = m & 15, kt = k >> 5, qq = (k >> 3) & 3, j = k & 7;
        sWA[((((l * 4 + rt) * 2 + kt) * 4 + qq) * 16 + mlo) * 8 + j] = (_Float16)Ws[pk_ * 64 + m];
    }
    // r19: layer-0 A-frags in LDS (identical for all waves; was 16 VGPR/lane).
    // sA0[rt][lane][j]: q(lane)==0 and j<3 -> W0[j][rt*16 + n(lane)], else 0.
    if (tid < 256) {
        int rt = tid >> 6, l = tid & 63, qq = l >> 4, nn = l & 15;
        union { f16x8 v; u32 dd[4]; _Float16 h[8]; } u;
        u.dd[0] = u.dd[1] = u.dd[2] = u.dd[3] = 0u;
        if (qq == 0) {
            u.h[0] = (_Float16)W0[0 * 64 + rt * 16 + nn];
            u.h[1] = (_Float16)W0[1 * 64 + rt * 16 + nn];
            u.h[2] = (_Float16)W0[2 * 64 + rt * 16 + nn];
        }
        *(f16x8*)&sA0[tid * 8] = u.v;
    }
    for (int i = tid; i < 64; i += BLK) {
        sB[0][i] = b0[i]; sB[1][i] = b1[i]; sB[2][i] = b2[i]; sB[3][i] = b3[i];
        sW4s[i] = W4[i];
    }
    if (tid < 192) ((float*)sW0r)[tid] = (float)(_Float16)W0[tid];
    if (tid == 0) sb4 = b4[0];

    const int wave = tid >> 6, lane = tid & 63;
    const int q = lane >> 4, n = lane & 15;
    const float alpha = __expf(log_alpha[0]);
    __syncthreads();

    // r18: wave-level mode split. Waves 0-3 PHYS (4 iters), 4-7 DATA2 (2 iters).
    // Wave w -> SIMD w&3, so each SIMD hosts 1 PHYS + 1 DATA wave per block.
    double dacc;
    if (wave < 4) {
        dacc = run_mode<false, 4>(xd, yd, xp, alpha, sWA, sA0, sB, sW0r, sW4s, sb4,
                                  q, n, lane, blockIdx.x * 4 + wave);
    } else {
        dacc = run_mode<true, 2>(xd, yd, xp, alpha, sWA, sA0, sB, sW0r, sW4s, sb4,
                                 q, n, lane, blockIdx.x * 4 + (wave - 4));
    }
    #pragma unroll
    for (int m = 1; m < 64; m <<= 1) dacc = dacc + shfl_xor_d(dacc, m);
    if (lane == 0) {
        if (wave < 4) sRedP[wave] = dacc;
        else          sRedD[wave - 4] = dacc;
    }
    __syncthreads();
    if (tid == 0)
        accg[2 * blockIdx.x + 0] = sRedP[0] + sRedP[1] + sRedP[2] + sRedP[3];
    if (tid == 64)
        accg[2 * blockIdx.x + 1] = sRedD[0] + sRedD[1] + sRedD[2] + sRedD[3];
}

__global__ void finalize_kernel(const double* __restrict__ ws,
                                const float* __restrict__ log_lambda,
                                const float* __restrict__ log_alpha,
                                float* __restrict__ out)
{
    __shared__ double sp[256], sd[256];
    int tid = threadIdx.x;
    double pd = 0.0, dd = 0.0;
    for (int i = tid; i < GRID; i += 256) {
        pd += ws[2 * i + 0];
        dd += ws[2 * i + 1];
    }
    sp[tid] = pd; sd[tid] = dd;
    __syncthreads();
    for (int s = 128; s > 0; s >>= 1) {
        if (tid < s) { sp[tid] += sp[tid + s]; sd[tid] += sd[tid + s]; }
        __syncthreads();
    }
    if (tid == 0) {
        float pde_loss  = (float)(sp[0] / (double)NSAMP);
        float data_loss = (float)(sd[0] / (double)NSAMP);
        float alpha = expf(log_alpha[0]);
        float lam   = expf(log_lambda[0]);
        out[0] = data_loss + lam * pde_loss;
        out[1] = data_loss;
        out[2] = pde_loss;
        out[3] = alpha;
        out[4] = lam;
    }
}

extern "C" void kernel_launch(void* const* d_in, const int* in_sizes, int n_in,
                              void* d_out, int out_size, void* d_ws, size_t ws_size,
                              hipStream_t stream) {
    const float* xd = (const float*)d_in[0];
    const float* yd = (const float*)d_in[1];
    const float* xp = (const float*)d_in[2];
    const float* W0 = (const float*)d_in[3];
    const float* b0 = (const float*)d_in[4];
    const float* W1 = (const float*)d_in[5];
    const float* b1 = (const float*)d_in[6];
    const float* W2 = (const float*)d_in[7];
    const float* b2 = (const float*)d_in[8];
    const float* W3 = (const float*)d_in[9];
    const float* b3 = (const float*)d_in[10];
    const float* W4 = (const float*)d_in[11];
    const float* b4 = (const float*)d_in[12];
    const float* log_lambda = (const float*)d_in[13];
    const float* log_alpha  = (const float*)d_in[14];
    float* out = (float*)d_out;
    double* acc = (double*)d_ws;   // 2*GRID doubles of per-block partials

    fused_kernel<<<GRID, BLK, 0, stream>>>(xd, yd, xp, W0, b0, W1, b1, W2, b2, W3, b3,
                                           W4, b4, log_alpha, acc);
    finalize_kernel<<<1, 256, 0, stream>>>(acc, log_lambda, log_alpha, out);
}